// Round 1
// baseline (482.802 us; speedup 1.0000x reference)
//
#include <hip/hip_runtime.h>
#include <hip/hip_bf16.h>
#include <math.h>

using short8 = __attribute__((ext_vector_type(8))) short;
using f32x4  = __attribute__((ext_vector_type(4))) float;

static __device__ __forceinline__ f32x4 mfma16(short8 a, short8 b, f32x4 c){
    return __builtin_amdgcn_mfma_f32_16x16x32_bf16(a, b, c, 0, 0, 0);
}

// round-to-nearest-even f32 -> bf16 bits (finite values only)
static __device__ __forceinline__ unsigned short bf16of(float f){
    unsigned int u = __float_as_uint(f);
    unsigned int lsb = (u >> 16) & 1u;
    u += 0x7fffu + lsb;
    return (unsigned short)(u >> 16);
}

// ---------------------------------------------------------------- prep
__global__ void prep_weights(const float* __restrict__ w1, const float* __restrict__ w2,
                             unsigned short* __restrict__ w1b, unsigned short* __restrict__ w2b){
    int i = blockIdx.x * 256 + threadIdx.x;
    if (i < 4*256*256){
        w1b[i] = bf16of(w1[i]);
        w2b[i] = bf16of(w2[i]);
    }
}

// ---------------------------------------------------------------- conv + LN
#define CH 16          // output h-rows per block
#define XR (CH + 6)    // input rows incl. halo
#define XW 262         // tile width incl. halo

__global__ __launch_bounds__(256) void conv_ln_kernel(
    const float* __restrict__ x, const float* __restrict__ conv_w,
    const float* __restrict__ conv_b, const float* __restrict__ ln_g,
    const float* __restrict__ ln_b, unsigned short* __restrict__ ynorm)
{
    __shared__ float xt[XR * XW];
    __shared__ float yt[CH * 256];

    const int tid = threadIdx.x;
    const int blk = blockIdx.x;
    const int ht = blk & 15;
    const int c  = (blk >> 4) & 255;
    const int b  = blk >> 12;
    const int h0 = ht * CH;

    const float* xplane = x + (((size_t)(b*256 + c)) << 16);

    // stage x tile (zero-padded halo)
    for (int i = tid; i < XR*XW; i += 256){
        int r = i / XW;
        int col = i - r*XW;
        int gh = h0 - 3 + r;
        int gw = col - 3;
        float v = 0.f;
        if ((unsigned)gh < 256u && (unsigned)gw < 256u)
            v = xplane[gh*256 + gw];
        xt[i] = v;
    }

    // conv weights: uniform address -> scalar loads
    float cwr[49];
    #pragma unroll
    for (int i = 0; i < 49; ++i) cwr[i] = conv_w[c*49 + i];
    const float cb = conv_b[c];

    __syncthreads();

    // one thread per w column, sliding-row accumulation over CH output rows
    const int w = tid;
    float acc[CH];
    #pragma unroll
    for (int r = 0; r < CH; ++r) acc[r] = 0.f;

    #pragma unroll
    for (int i = 0; i < XR; ++i){
        #pragma unroll
        for (int j = 0; j < 7; ++j){
            float v = xt[i*XW + w + j];
            #pragma unroll
            for (int ro = 0; ro < CH; ++ro){
                if (ro >= i - 6 && ro <= i)      // constant-folds after unroll
                    acc[ro] = fmaf(v, cwr[(i - ro)*7 + j], acc[ro]);
            }
        }
    }

    #pragma unroll
    for (int r = 0; r < CH; ++r) yt[r*256 + w] = acc[r] + cb;

    __syncthreads();

    // LayerNorm over w: one wave per row
    const int lane = tid & 63;
    const int wid  = tid >> 6;
    float lg[4], lb[4];
    #pragma unroll
    for (int q = 0; q < 4; ++q){ lg[q] = ln_g[lane + 64*q]; lb[q] = ln_b[lane + 64*q]; }

    for (int rr = 0; rr < CH/4; ++rr){
        int row = wid*(CH/4) + rr;
        float v[4], s = 0.f, ss = 0.f;
        #pragma unroll
        for (int q = 0; q < 4; ++q){
            v[q] = yt[row*256 + lane + 64*q];
            s += v[q]; ss += v[q]*v[q];
        }
        #pragma unroll
        for (int off = 32; off > 0; off >>= 1){
            s  += __shfl_xor(s, off);
            ss += __shfl_xor(ss, off);
        }
        float mu  = s * (1.f/256.f);
        float var = ss * (1.f/256.f) - mu*mu;
        float rs  = rsqrtf(var + 1e-5f);
        size_t M = (size_t)((b*256 + c)*256 + h0 + row);
        unsigned short* dst = ynorm + M*256;
        #pragma unroll
        for (int q = 0; q < 4; ++q){
            float o = (v[q] - mu)*rs*lg[q] + lb[q];
            dst[lane + 64*q] = bf16of(o);
        }
    }
}

// ---------------------------------------------------------------- fused MLP + transpose + residual
// block: 256 threads = 4 waves; M-tile = 64 rows (one (b,c) plane slice)
// waves split the N dimension (4 nf each) so weight reads are not duplicated.
__global__ __launch_bounds__(256, 2) void mlp_kernel(
    const unsigned short* __restrict__ ynorm,
    const short* __restrict__ w1b, const short* __restrict__ w2b,
    const float* __restrict__ b1, const float* __restrict__ b2,
    const float* __restrict__ x, float* __restrict__ out)
{
    __shared__ __align__(16) char smem[69632];
    short* Ash = (short*)smem;               // [64][264] bf16 (padded)
    short* Hsh = (short*)(smem + 33792);     // [64][264] bf16 (padded)
    float* OT  = (float*)smem;               // [256][68] f32 (aliases A/H, used after)

    const int tid  = threadIdx.x;
    const int lane = tid & 63;
    const int wid  = tid >> 6;
    const int M0 = blockIdx.x * 64;
    const int b = M0 >> 16, c = (M0 >> 8) & 255, h0 = M0 & 255;

    // stage A tile (64 x 256 bf16)
    {
        const uint4* src = reinterpret_cast<const uint4*>(ynorm + (size_t)M0*256);
        for (int i = tid; i < 2048; i += 256){
            int row = i >> 5, g = i & 31;
            uint4 v = src[row*32 + g];
            *reinterpret_cast<uint4*>(Ash + row*264 + g*8) = v;
        }
    }
    __syncthreads();

    const int l15  = lane & 15;
    const int kg   = lane >> 4;   // 0..3
    const int koff = kg * 8;

    f32x4 acc2[4][4] = {};

    for (int oc = 0; oc < 4; ++oc){
        f32x4 acc1[4][4] = {};
        #pragma unroll
        for (int ks = 0; ks < 8; ++ks){
            short8 afr[4], bfr[4];
            #pragma unroll
            for (int mf = 0; mf < 4; ++mf)
                afr[mf] = *reinterpret_cast<const short8*>(Ash + (mf*16 + l15)*264 + ks*32 + koff);
            #pragma unroll
            for (int nfi = 0; nfi < 4; ++nfi){
                int o = oc*256 + (wid*4 + nfi)*16 + l15;
                bfr[nfi] = *reinterpret_cast<const short8*>(w1b + o*256 + ks*32 + koff);
            }
            #pragma unroll
            for (int mf = 0; mf < 4; ++mf){
                #pragma unroll
                for (int nfi = 0; nfi < 4; ++nfi)
                    acc1[mf][nfi] = mfma16(afr[mf], bfr[nfi], acc1[mf][nfi]);
            }
        }
        __syncthreads();   // previous chunk's Hsh reads complete
        // bias + exact GELU -> Hsh (bf16)
        #pragma unroll
        for (int nfi = 0; nfi < 4; ++nfi){
            int col = (wid*4 + nfi)*16 + l15;
            float bb = b1[oc*256 + col];
            #pragma unroll
            for (int mf = 0; mf < 4; ++mf){
                int rbase = mf*16 + kg*4;
                #pragma unroll
                for (int r = 0; r < 4; ++r){
                    float v = acc1[mf][nfi][r] + bb;
                    float g = 0.5f * v * (1.f + erff(v * 0.70710678118654752f));
                    Hsh[(rbase + r)*264 + col] = (short)bf16of(g);
                }
            }
        }
        __syncthreads();
        // GEMM2 partial over this oc chunk
        #pragma unroll
        for (int ks = 0; ks < 8; ++ks){
            short8 hfr[4], bfr[4];
            #pragma unroll
            for (int mf = 0; mf < 4; ++mf)
                hfr[mf] = *reinterpret_cast<const short8*>(Hsh + (mf*16 + l15)*264 + ks*32 + koff);
            #pragma unroll
            for (int nfi = 0; nfi < 4; ++nfi){
                int wcol = (wid*4 + nfi)*16 + l15;
                bfr[nfi] = *reinterpret_cast<const short8*>(w2b + wcol*1024 + oc*256 + ks*32 + koff);
            }
            #pragma unroll
            for (int mf = 0; mf < 4; ++mf){
                #pragma unroll
                for (int nfi = 0; nfi < 4; ++nfi)
                    acc2[mf][nfi] = mfma16(hfr[mf], bfr[nfi], acc2[mf][nfi]);
            }
        }
    }
    __syncthreads();
    // transpose into OT[w][h] (+b2)
    #pragma unroll
    for (int nfi = 0; nfi < 4; ++nfi){
        int w = (wid*4 + nfi)*16 + l15;
        float bb = b2[w];
        #pragma unroll
        for (int mf = 0; mf < 4; ++mf){
            int hb = mf*16 + kg*4;
            #pragma unroll
            for (int r = 0; r < 4; ++r)
                OT[w*68 + hb + r] = acc2[mf][nfi][r] + bb;
        }
    }
    __syncthreads();
    // residual + store: out[b, w, c, h0..h0+63]
    for (int k = 0; k < 16; ++k){
        int idx = k*256 + tid;
        int w = idx >> 4, f4 = idx & 15;
        size_t o = (((size_t)(b*256 + w)*256 + c) << 8) + (size_t)(h0 + f4*4);
        float4 xa = *reinterpret_cast<const float4*>(x + o);
        float4 rv;
        rv.x = OT[w*68 + f4*4 + 0] + xa.x;
        rv.y = OT[w*68 + f4*4 + 1] + xa.y;
        rv.z = OT[w*68 + f4*4 + 2] + xa.z;
        rv.w = OT[w*68 + f4*4 + 3] + xa.w;
        *reinterpret_cast<float4*>(out + o) = rv;
    }
}

// ---------------------------------------------------------------- launch
extern "C" void kernel_launch(void* const* d_in, const int* in_sizes, int n_in,
                              void* d_out, int out_size, void* d_ws, size_t ws_size,
                              hipStream_t stream)
{
    const float* x      = (const float*)d_in[0];
    const float* conv_w = (const float*)d_in[1];
    const float* conv_b = (const float*)d_in[2];
    const float* ln_g   = (const float*)d_in[3];
    const float* ln_b   = (const float*)d_in[4];
    const float* w1     = (const float*)d_in[5];
    const float* b1     = (const float*)d_in[6];
    const float* w2     = (const float*)d_in[7];
    const float* b2     = (const float*)d_in[8];
    float* out = (float*)d_out;

    unsigned short* ynorm = (unsigned short*)d_ws;                          // 67,108,864 B
    unsigned short* w1b   = (unsigned short*)((char*)d_ws + 67108864);      //    524,288 B
    unsigned short* w2b   = (unsigned short*)((char*)d_ws + 67108864 + 524288);

    hipLaunchKernelGGL(prep_weights, dim3(1024), dim3(256), 0, stream, w1, w2, w1b, w2b);
    hipLaunchKernelGGL(conv_ln_kernel, dim3(8192), dim3(256), 0, stream,
                       x, conv_w, conv_b, ln_g, ln_b, ynorm);
    hipLaunchKernelGGL(mlp_kernel, dim3(2048), dim3(256), 0, stream,
                       ynorm, (const short*)w1b, (const short*)w2b, b1, b2, x, out);
}